// Round 6
// baseline (158.508 us; speedup 1.0000x reference)
//
#include <hip/hip_runtime.h>

#define N_NODES 4096
#define D_DIM   512
#define E_EDGES 131072
#define NWORDS  128   // 4096/32
#define MLP_BLOCKS 256

typedef __bf16 bf16;
typedef __bf16 bf16x4 __attribute__((ext_vector_type(4)));
typedef __bf16 bf16x8 __attribute__((ext_vector_type(8)));
typedef float  f32x4  __attribute__((ext_vector_type(4)));
typedef unsigned int u32;

// ---------------- workspace layout ----------------
static const size_t OFF_W0B = 0;                                    // W0 bf16 512 KiB
static const size_t OFF_W1B = OFF_W0B + (size_t)D_DIM*D_DIM*2;
static const size_t OFF_W2B = OFF_W1B + (size_t)D_DIM*D_DIM*2;
static const size_t OFF_ANG = OFF_W2B + (size_t)D_DIM*D_DIM*2;      // angles fp32 (plain stores)
static const size_t OFF_H1  = OFF_ANG + N_NODES*4;                  // hop1 accum (carries 0.25)
static const size_t OFF_A2V = OFF_H1  + N_NODES*4;                  // a2 fp32
static const size_t OFF_TP  = OFF_A2V + N_NODES*4;                  // Tpart[1024]
static const size_t OFF_AB  = OFF_TP  + 1024*4;                     // A bits 2 MiB
static const size_t OFF_A2B = OFF_AB  + (size_t)N_NODES*NWORDS*4;   // A^2 bits
static const size_t OFF_A3B = OFF_A2B + (size_t)N_NODES*NWORDS*4;   // A^3 bits

__device__ __forceinline__ bf16x8 cvt8(float4 lo, float4 hi) {
    bf16x8 r;
    r[0] = (bf16)lo.x; r[1] = (bf16)lo.y; r[2] = (bf16)lo.z; r[3] = (bf16)lo.w;
    r[4] = (bf16)hi.x; r[5] = (bf16)hi.y; r[6] = (bf16)hi.z; r[7] = (bf16)hi.w;
    return r;
}

// ---------------- prep: W casts + zero Ab + zero h1 ----------------
// LESSONS: (r2) device-scope spin barriers ~100us each — never fuse across a global
// dependency; dispatch boundary is the cheap primitive. (r3) GEMM staging path
// neutral. (r5) GEMM LDS swizzle ~-2us only. => kernels are near floor; the mass
// is per-dispatch fixed cost. This round: 7 -> 5 dispatches via row-local MLP fusion.
__global__ __launch_bounds__(256)
void prep(const float* __restrict__ W0, const float* __restrict__ W1,
          const float* __restrict__ W2,
          bf16* __restrict__ W0b, bf16* __restrict__ W1b, bf16* __restrict__ W2b,
          u32* __restrict__ Ab, float* __restrict__ h1)
{
    const int bx = blockIdx.x, t = threadIdx.x;
    if (bx < 192) {
        // cast W0/W1/W2: 3 x 64 blocks x 4096 floats
        const float* src = (bx < 64) ? W0 : (bx < 128) ? W1 : W2;
        bf16* dst = (bx < 64) ? W0b : (bx < 128) ? W1b : W2b;
        size_t base = (size_t)(bx & 63) * 4096;
        #pragma unroll
        for (int i = 0; i < 4; ++i) {
            size_t e = base + (size_t)(i * 256 + t) * 4;
            float4 v = *(const float4*)(src + e);
            bf16x4 o; o.x = (bf16)v.x; o.y = (bf16)v.y; o.z = (bf16)v.z; o.w = (bf16)v.w;
            *(bf16x4*)(dst + e) = o;
        }
    } else if (bx < 320) {
        // zero Ab (poisoned 0xAA): 128 blocks x 1024 uint4
        uint4* dst = (uint4*)Ab + (size_t)(bx - 192) * 1024;
        uint4 z = {0u, 0u, 0u, 0u};
        #pragma unroll
        for (int i = 0; i < 4; ++i) dst[i * 256 + t] = z;
    } else {
        for (int i = t; i < N_NODES; i += 256) h1[i] = 0.f;
    }
}

// 16x64 output tile per wave, K=512. A from swizzled LDS x-tile, B streamed
// directly from global W (bf16 row-major [out][in]); each quad consumes full
// 64B lines of 16 W-rows -> coalesced, L2-resident (W fits all per-XCD L2s).
__device__ __forceinline__ void gemm16x64(const bf16 (*xin)[512], const bf16* __restrict__ Wl,
                                          int col0, int lq, int quad, f32x4 acc[4])
{
    #pragma unroll
    for (int ks = 0; ks < 16; ++ks) {
        bf16x8 a = *(const bf16x8*)&xin[lq][(((ks * 4 + quad) ^ (lq & 7)) << 3)];
        #pragma unroll
        for (int f = 0; f < 4; ++f) {
            bf16x8 b = *(const bf16x8*)(Wl + (size_t)(col0 + f * 16 + lq) * 512 + ks * 32 + quad * 8);
            acc[f] = __builtin_amdgcn_mfma_f32_16x16x32_bf16(a, b, acc[f], 0, 0, 0);
        }
    }
}

__device__ __forceinline__ void store_act(bf16 (*xout)[512], const f32x4 acc[4],
                                          int col0, int lq, int quad,
                                          const float* __restrict__ bias, float sl)
{
    #pragma unroll
    for (int f = 0; f < 4; ++f) {
        int col = col0 + f * 16 + lq;
        float bv = bias ? bias[col] : 0.f;
        int c = col >> 3, e = col & 7;
        #pragma unroll
        for (int r = 0; r < 4; ++r) {
            int row = quad * 4 + r;     // C layout: col=lane&15, row=(lane>>4)*4+r
            float v = acc[f][r] + bv;
            v = (v >= 0.f) ? v : sl * v;
            xout[row][((c ^ (row & 7)) << 3) + e] = (bf16)v;
        }
    }
}

// ---------------- fused row-local MLP (coeffs -> ang) + adj-build tail ----------------
// 256 MLP blocks x 512 thr: block owns 16 rows; 3 layers ping-pong in LDS; final
// Wo-projection via shfl + cross-wave LDS reduce -> plain ang store (no atomics,
// no ang init). Tail: 128 adj-build blocks.
__global__ __launch_bounds__(512)
void mlp_fused(const float* __restrict__ coeffs,
               const bf16* __restrict__ W0b, const bf16* __restrict__ W1b,
               const bf16* __restrict__ W2b,
               const float* __restrict__ b0, const float* __restrict__ pa0,
               const float* __restrict__ pa1, const float* __restrict__ pa2,
               const float* __restrict__ Wo, const float* __restrict__ bo,
               float* __restrict__ ang,
               const int* __restrict__ esrc, const int* __restrict__ edst,
               u32* __restrict__ AbOut)
{
    __shared__ bf16 xa[16][512];     // 16 KiB, XOR-swizzled chunks: c' = c ^ (row&7)
    __shared__ bf16 xb[16][512];     // 16 KiB
    __shared__ float s_ang[8][16];
    const int bx = blockIdx.x, t = threadIdx.x;

    if (bx < MLP_BLOCKS) {
        const int wave = t >> 6, lane = t & 63;
        const int quad = lane >> 4, lq = lane & 15;
        const int rb = bx * 16;
        const int col0 = wave * 64;

        // stage x0: 16 rows x 512 cols, fp32 -> bf16, swizzled. 16 cols/thread.
        {
            int r = t >> 5;
            int kc = (t & 31) * 16;
            const float* src = coeffs + (size_t)(rb + r) * 512 + kc;
            float4 v0 = *(const float4*)(src);
            float4 v1 = *(const float4*)(src + 4);
            float4 v2 = *(const float4*)(src + 8);
            float4 v3 = *(const float4*)(src + 12);
            int c0 = kc >> 3;
            *(bf16x8*)&xa[r][((c0 ^ (r & 7)) << 3)]       = cvt8(v0, v1);
            *(bf16x8*)&xa[r][(((c0 + 1) ^ (r & 7)) << 3)] = cvt8(v2, v3);
        }
        __syncthreads();

        {   // layer 0: xa -> xb (bias + prelu)
            f32x4 acc[4] = {};
            gemm16x64(xa, W0b, col0, lq, quad, acc);
            store_act(xb, acc, col0, lq, quad, b0, pa0[0]);
        }
        __syncthreads();
        {   // layer 1: xb -> xa (prelu)
            f32x4 acc[4] = {};
            gemm16x64(xb, W1b, col0, lq, quad, acc);
            store_act(xa, acc, col0, lq, quad, nullptr, pa1[0]);
        }
        __syncthreads();
        {   // layer 2 + Wo projection -> ang
            f32x4 acc[4] = {};
            gemm16x64(xa, W2b, col0, lq, quad, acc);
            const float sl = pa2[0];
            float wo[4];
            #pragma unroll
            for (int f = 0; f < 4; ++f) wo[f] = Wo[col0 + f * 16 + lq];
            #pragma unroll
            for (int r = 0; r < 4; ++r) {
                float p = 0.f;
                #pragma unroll
                for (int f = 0; f < 4; ++f) {
                    float v = acc[f][r];
                    v = (v >= 0.f) ? v : sl * v;
                    p += v * wo[f];
                }
                #pragma unroll
                for (int m = 1; m < 16; m <<= 1) p += __shfl_xor(p, m, 64);
                if (lq == 0) s_ang[wave][quad * 4 + r] = p;
            }
        }
        __syncthreads();
        if (t < 16) {
            float s = bo[0];
            #pragma unroll
            for (int w2 = 0; w2 < 8; ++w2) s += s_ang[w2][t];
            ang[rb + t] = s;
        }
    } else {
        // build boolean adjacency bits — 128 blocks x 512 thr (Ab zeroed by prep)
        int base = (bx - MLP_BLOCKS) * 512 + t;
        for (int e = base; e < E_EDGES; e += 128 * 512) {
            int r = esrc[e], c = edst[e];
            atomicOr(&AbOut[(size_t)r * NWORDS + (c >> 5)], 1u << (c & 31));
        }
    }
}

// ---------------- row-OR body (shared by K3/K4 tails) ----------------
__device__ __forceinline__ void row_or(int row, int wave, int lane,
                                       int* s_cnt, int (*s_list)[256],
                                       const u32* __restrict__ P, const u32* __restrict__ Q,
                                       u32* __restrict__ BOut)
{
    if (lane == 0) s_cnt[wave] = 0;
    __syncthreads();
    const u32* prow = P + (size_t)row * NWORDS;
    #pragma unroll
    for (int h = 0; h < 2; ++h) {
        u32 bits = prow[h * 64 + lane];
        int base = (h * 64 + lane) * 32;
        while (bits) {
            int b = __ffs(bits) - 1; bits &= bits - 1;
            int pos = atomicAdd(&s_cnt[wave], 1);
            if (pos < 256) s_list[wave][pos] = base + b;
        }
    }
    __syncthreads();
    int cnt = min(s_cnt[wave], 256);
    u32 acc0 = 0, acc1 = 0;
    int j = 0;
    for (; j + 4 <= cnt; j += 4) {
        int i0 = s_list[wave][j], i1 = s_list[wave][j + 1];
        int i2 = s_list[wave][j + 2], i3 = s_list[wave][j + 3];
        const u32* q0 = Q + (size_t)i0 * NWORDS;
        const u32* q1 = Q + (size_t)i1 * NWORDS;
        const u32* q2 = Q + (size_t)i2 * NWORDS;
        const u32* q3 = Q + (size_t)i3 * NWORDS;
        u32 x0 = q0[lane], x1 = q1[lane], x2 = q2[lane], x3 = q3[lane];
        u32 y0 = q0[64 + lane], y1 = q1[64 + lane], y2 = q2[64 + lane], y3 = q3[64 + lane];
        acc0 |= x0 | x1 | x2 | x3;
        acc1 |= y0 | y1 | y2 | y3;
    }
    for (; j < cnt; ++j) {
        const u32* q = Q + (size_t)s_list[wave][j] * NWORDS;
        acc0 |= q[lane]; acc1 |= q[64 + lane];
    }
    BOut[(size_t)row * NWORDS + lane]      = acc0;
    BOut[(size_t)row * NWORDS + 64 + lane] = acc1;
}

// ---------------- K3: hop1 edge scatter (512 blocks) + A2 = bool(A@A) (1024 blocks) ----------------
__global__ __launch_bounds__(256)
void hop1_rowor(const int* __restrict__ src, const int* __restrict__ dst,
                const float* __restrict__ ang, float* __restrict__ h1,
                const u32* __restrict__ P, const u32* __restrict__ Q, u32* __restrict__ BOut)
{
    __shared__ int s_cnt[4];
    __shared__ int s_list[4][256];
    const int bx = blockIdx.x, t = threadIdx.x;
    const int wave = t >> 6, lane = t & 63;
    if (bx < 512) {
        int e = bx * 256 + t;
        atomicAdd(&h1[src[e]], 0.25f * ang[dst[e]]);
    } else {
        row_or((bx - 512) * 4 + wave, wave, lane, s_cnt, s_list, P, Q, BOut);
    }
}

// ---------------- K4: bmv2 (1024 blocks) + A3 = bool(A@A2) (1024 blocks) ----------------
// bmv2: a2[i] = a1(i) + (1/9)*sum_{j in A2-row(i)} a1(j); a1 = ang + h1, staged in LDS (r4).
__global__ __launch_bounds__(256)
void bmv2_rowor(const u32* __restrict__ A2, const float* __restrict__ ang,
                const float* __restrict__ h1, float* __restrict__ a2,
                float* __restrict__ Tpart,
                const u32* __restrict__ P, const u32* __restrict__ Q, u32* __restrict__ BOut)
{
    __shared__ float aLds[N_NODES];   // 16 KiB
    __shared__ float s_red[4];
    __shared__ int s_cnt[4];
    __shared__ int s_list[4][256];
    const int bx = blockIdx.x, t = threadIdx.x;
    const int wave = t >> 6, lane = t & 63;

    if (bx < 1024) {
        #pragma unroll
        for (int i = 0; i < 4; ++i) {
            int e = (i * 256 + t) * 4;
            float4 va = *(const float4*)(ang + e);
            float4 vh = *(const float4*)(h1 + e);
            float4 o; o.x = va.x + vh.x; o.y = va.y + vh.y; o.z = va.z + vh.z; o.w = va.w + vh.w;
            *(float4*)(aLds + e) = o;
        }
        __syncthreads();

        int row = bx * 4 + wave;
        float s = 0.f;
        #pragma unroll
        for (int h = 0; h < 2; ++h) {
            u32 bits = A2[(size_t)row * NWORDS + h * 64 + lane];
            int base = (h * 64 + lane) * 32;
            while (bits) {
                int b = __ffs(bits) - 1;
                bits &= bits - 1;
                s += aLds[base + b];
            }
        }
        #pragma unroll
        for (int off = 32; off > 0; off >>= 1) s += __shfl_down(s, off, 64);
        if (lane == 0) {
            float val = aLds[row] + (1.f / 9.f) * s;
            a2[row] = val;
            s_red[wave] = val;
        }
        __syncthreads();
        if (t == 0)
            Tpart[bx] = s_red[0] + s_red[1] + s_red[2] + s_red[3];
    } else {
        row_or((bx - 1024) * 4 + wave, wave, lane, s_cnt, s_list, P, Q, BOut);
    }
}

// ---------------- K5: out[i] = a2[i] + (1/16)*(T - sum_{j NOT in A3-row(i)} a2[j]) ----------------
__global__ __launch_bounds__(256)
void bits_matvec3(const u32* __restrict__ A3, const float* __restrict__ a2,
                  const float* __restrict__ Tpart, float* __restrict__ out)
{
    __shared__ float aLds[N_NODES];   // 16 KiB
    __shared__ float s_part[4];
    const int t = threadIdx.x, wave = t >> 6, lane = t & 63;

    #pragma unroll
    for (int i = 0; i < 4; ++i) {
        int e = (i * 256 + t) * 4;
        *(float4*)(aLds + e) = *(const float4*)(a2 + e);
    }

    float tsum = 0.f;
    #pragma unroll
    for (int i = 0; i < 4; ++i) tsum += Tpart[i * 256 + t];
    #pragma unroll
    for (int off = 32; off > 0; off >>= 1) tsum += __shfl_down(tsum, off, 64);
    if (lane == 0) s_part[wave] = tsum;
    __syncthreads();                      // covers aLds stage + s_part
    const float T = s_part[0] + s_part[1] + s_part[2] + s_part[3];

    int row = blockIdx.x * 4 + wave;
    float s = 0.f;
    #pragma unroll
    for (int h = 0; h < 2; ++h) {
        u32 bits = ~A3[(size_t)row * NWORDS + h * 64 + lane];   // complement (~97% dense)
        int base = (h * 64 + lane) * 32;
        while (bits) {
            int b = __ffs(bits) - 1;
            bits &= bits - 1;
            s += aLds[base + b];
        }
    }
    #pragma unroll
    for (int off = 32; off > 0; off >>= 1) s += __shfl_down(s, off, 64);
    if (lane == 0) out[row] = aLds[row] + (1.f / 16.f) * (T - s);
}

extern "C" void kernel_launch(void* const* d_in, const int* in_sizes, int n_in,
                              void* d_out, int out_size, void* d_ws, size_t ws_size,
                              hipStream_t stream) {
    const float* coeffs = (const float*)d_in[0];
    const int*   edges  = (const int*)d_in[1];
    const float* W0     = (const float*)d_in[2];
    const float* b0     = (const float*)d_in[3];
    const float* pa0    = (const float*)d_in[4];
    const float* W1     = (const float*)d_in[5];
    const float* pa1    = (const float*)d_in[6];
    const float* W2     = (const float*)d_in[7];
    const float* pa2    = (const float*)d_in[8];
    const float* Wo     = (const float*)d_in[9];
    const float* bo     = (const float*)d_in[10];
    float* out = (float*)d_out;

    char* ws = (char*)d_ws;
    bf16*  W0b  = (bf16*)(ws + OFF_W0B);
    bf16*  W1b  = (bf16*)(ws + OFF_W1B);
    bf16*  W2b  = (bf16*)(ws + OFF_W2B);
    float* ang  = (float*)(ws + OFF_ANG);
    float* h1   = (float*)(ws + OFF_H1);
    float* a2v  = (float*)(ws + OFF_A2V);
    float* Tp   = (float*)(ws + OFF_TP);
    u32*   Ab   = (u32*)(ws + OFF_AB);
    u32*   A2b  = (u32*)(ws + OFF_A2B);
    u32*   A3b  = (u32*)(ws + OFF_A3B);

    const int* srcp = edges;
    const int* dstp = edges + E_EDGES;

    // K1: cast W0/W1/W2 -> bf16, zero Ab, zero h1
    prep<<<321, 256, 0, stream>>>(W0, W1, W2, W0b, W1b, W2b, Ab, h1);

    // K2: row-local fused MLP (coeffs -> ang, plain stores) + adj-build
    mlp_fused<<<MLP_BLOCKS + 128, 512, 0, stream>>>(coeffs, W0b, W1b, W2b, b0, pa0, pa1, pa2,
                                                    Wo, bo, ang, srcp, dstp, Ab);

    // K3: hop1 scatter (needs ang) + A2 = bool(A@A) (needs Ab)
    hop1_rowor<<<1536, 256, 0, stream>>>(srcp, dstp, ang, h1, Ab, Ab, A2b);

    // K4: bmv2 (needs h1, A2) + A3 = bool(A@A2)
    bmv2_rowor<<<2048, 256, 0, stream>>>(A2b, ang, h1, a2v, Tp, Ab, A2b, A3b);

    // K5: bmv3
    bits_matvec3<<<1024, 256, 0, stream>>>(A3b, a2v, Tp, out);
}

// Round 8
// 129.081 us; speedup vs baseline: 1.2280x; 1.2280x over previous
//
#include <hip/hip_runtime.h>

#define N_NODES 4096
#define D_DIM   512
#define E_EDGES 131072
#define NWORDS  128   // 4096/32
#define MLP_BLOCKS 256

typedef __bf16 bf16;
typedef __bf16 bf16x4 __attribute__((ext_vector_type(4)));
typedef __bf16 bf16x8 __attribute__((ext_vector_type(8)));
typedef float  f32x4  __attribute__((ext_vector_type(4)));
typedef unsigned int u32;

// ---------------- workspace layout ----------------
// W*P are PACKED fragment-ready layouts: [colblk(8)][ks(16)][f(4)][lane(64)][8elem]
static const size_t OFF_W0P = 0;                                    // 512 KiB each
static const size_t OFF_W1P = OFF_W0P + (size_t)D_DIM*D_DIM*2;
static const size_t OFF_W2P = OFF_W1P + (size_t)D_DIM*D_DIM*2;
static const size_t OFF_ANG = OFF_W2P + (size_t)D_DIM*D_DIM*2;      // angles fp32 (plain stores)
static const size_t OFF_H1  = OFF_ANG + N_NODES*4;                  // hop1 accum (carries 0.25)
static const size_t OFF_A2V = OFF_H1  + N_NODES*4;                  // a2 fp32
static const size_t OFF_TP  = OFF_A2V + N_NODES*4;                  // Tpart[1024]
static const size_t OFF_AB  = OFF_TP  + 1024*4;                     // A bits 2 MiB
static const size_t OFF_A2B = OFF_AB  + (size_t)N_NODES*NWORDS*4;   // A^2 bits
static const size_t OFF_A3B = OFF_A2B + (size_t)N_NODES*NWORDS*4;   // A^3 bits

__device__ __forceinline__ bf16x8 cvt8(float4 lo, float4 hi) {
    bf16x8 r;
    r[0] = (bf16)lo.x; r[1] = (bf16)lo.y; r[2] = (bf16)lo.z; r[3] = (bf16)lo.w;
    r[4] = (bf16)hi.x; r[5] = (bf16)hi.y; r[6] = (bf16)hi.z; r[7] = (bf16)hi.w;
    return r;
}

// ---------------- prep: W fp32 -> PACKED bf16 fragments + zero Ab + zero h1 ----------------
// r6 lesson: streaming W[col][k] straight from global put 64 lanes on 1KB-strided
// 16B chunks -> 64 cachelines per wave-load, latency-bound at 4% VALU (55us kernel).
// Fix (HK pre-swizzled-global pattern): prep permutes W so a wave's B-fragment for
// (colblk,ks,f) is ONE contiguous 1KB block: chunk p <-> (colblk,ks,f,lane) with
//   col = colblk*64 + f*16 + (lane&15),  k = ks*32 + (lane>>4)*8.
// LESSONS r2/r3/r5: no device-scope barriers (~100us each); GEMM staging/swizzle
// micro-tweaks are ~0-2us; dispatch-count and access-pattern are the real levers.
// (r7: resubmitted unchanged — GPU acquisition timeout, never measured.)
__global__ __launch_bounds__(256)
void prep(const float* __restrict__ W0, const float* __restrict__ W1,
          const float* __restrict__ W2,
          bf16* __restrict__ W0p, bf16* __restrict__ W1p, bf16* __restrict__ W2p,
          u32* __restrict__ Ab, float* __restrict__ h1)
{
    const int bx = blockIdx.x, t = threadIdx.x;
    if (bx < 192) {
        const int layer = bx >> 6;
        const float* src = (layer == 0) ? W0 : (layer == 1) ? W1 : W2;
        bf16* dst = (layer == 0) ? W0p : (layer == 1) ? W1p : W2p;
        #pragma unroll
        for (int i = 0; i < 2; ++i) {
            int p = (bx & 63) * 512 + i * 256 + t;    // chunk index in [0, 32768)
            int colblk = p >> 12, ks = (p >> 8) & 15, f = (p >> 6) & 3, lane = p & 63;
            int col = colblk * 64 + f * 16 + (lane & 15);
            int k   = ks * 32 + (lane >> 4) * 8;
            const float* s = src + (size_t)col * D_DIM + k;
            float4 lo = *(const float4*)(s);
            float4 hi = *(const float4*)(s + 4);
            *(bf16x8*)(dst + (size_t)p * 8) = cvt8(lo, hi);
        }
    } else if (bx < 320) {
        // zero Ab (poisoned 0xAA): 128 blocks x 1024 uint4
        uint4* dst = (uint4*)Ab + (size_t)(bx - 192) * 1024;
        uint4 z = {0u, 0u, 0u, 0u};
        #pragma unroll
        for (int i = 0; i < 4; ++i) dst[i * 256 + t] = z;
    } else {
        for (int i = t; i < N_NODES; i += 256) h1[i] = 0.f;
    }
}

// 16x64 output tile per wave, K=512. A from swizzled LDS x-tile, B = packed W:
// one coalesced 1KB wave-load per (ks,f), L2-resident, all loads independent.
__device__ __forceinline__ void gemm16x64(const bf16 (*xin)[512], const bf16* __restrict__ Wp,
                                          int wave, int lane, int lq, int quad, f32x4 acc[4])
{
    #pragma unroll
    for (int ks = 0; ks < 16; ++ks) {
        bf16x8 a = *(const bf16x8*)&xin[lq][(((ks * 4 + quad) ^ (lq & 7)) << 3)];
        #pragma unroll
        for (int f = 0; f < 4; ++f) {
            bf16x8 b = *(const bf16x8*)(Wp + ((size_t)((wave * 16 + ks) * 4 + f) * 64 + lane) * 8);
            acc[f] = __builtin_amdgcn_mfma_f32_16x16x32_bf16(a, b, acc[f], 0, 0, 0);
        }
    }
}

__device__ __forceinline__ void store_act(bf16 (*xout)[512], const f32x4 acc[4],
                                          int col0, int lq, int quad,
                                          const float* __restrict__ bias, float sl)
{
    #pragma unroll
    for (int f = 0; f < 4; ++f) {
        int col = col0 + f * 16 + lq;
        float bv = bias ? bias[col] : 0.f;
        int c = col >> 3, e = col & 7;
        #pragma unroll
        for (int r = 0; r < 4; ++r) {
            int row = quad * 4 + r;     // C layout: col=lane&15, row=(lane>>4)*4+r
            float v = acc[f][r] + bv;
            v = (v >= 0.f) ? v : sl * v;
            xout[row][((c ^ (row & 7)) << 3) + e] = (bf16)v;
        }
    }
}

// ---------------- fused row-local MLP (coeffs -> ang) + adj-build tail ----------------
// 256 MLP blocks x 512 thr: block owns 16 rows; 3 layers ping-pong in LDS; final
// Wo-projection via shfl + cross-wave LDS reduce -> plain ang store. Tail: 128 adj blocks.
__global__ __launch_bounds__(512)
void mlp_fused(const float* __restrict__ coeffs,
               const bf16* __restrict__ W0p, const bf16* __restrict__ W1p,
               const bf16* __restrict__ W2p,
               const float* __restrict__ b0, const float* __restrict__ pa0,
               const float* __restrict__ pa1, const float* __restrict__ pa2,
               const float* __restrict__ Wo, const float* __restrict__ bo,
               float* __restrict__ ang,
               const int* __restrict__ esrc, const int* __restrict__ edst,
               u32* __restrict__ AbOut)
{
    __shared__ bf16 xa[16][512];     // 16 KiB, XOR-swizzled chunks: c' = c ^ (row&7)
    __shared__ bf16 xb[16][512];     // 16 KiB
    __shared__ float s_ang[8][16];
    const int bx = blockIdx.x, t = threadIdx.x;

    if (bx < MLP_BLOCKS) {
        const int wave = t >> 6, lane = t & 63;
        const int quad = lane >> 4, lq = lane & 15;
        const int rb = bx * 16;
        const int col0 = wave * 64;

        // stage x0: 16 rows x 512 cols, fp32 -> bf16, swizzled. 16 cols/thread.
        {
            int r = t >> 5;
            int kc = (t & 31) * 16;
            const float* src = coeffs + (size_t)(rb + r) * 512 + kc;
            float4 v0 = *(const float4*)(src);
            float4 v1 = *(const float4*)(src + 4);
            float4 v2 = *(const float4*)(src + 8);
            float4 v3 = *(const float4*)(src + 12);
            int c0 = kc >> 3;
            *(bf16x8*)&xa[r][((c0 ^ (r & 7)) << 3)]       = cvt8(v0, v1);
            *(bf16x8*)&xa[r][(((c0 + 1) ^ (r & 7)) << 3)] = cvt8(v2, v3);
        }
        __syncthreads();

        {   // layer 0: xa -> xb (bias + prelu)
            f32x4 acc[4] = {};
            gemm16x64(xa, W0p, wave, lane, lq, quad, acc);
            store_act(xb, acc, col0, lq, quad, b0, pa0[0]);
        }
        __syncthreads();
        {   // layer 1: xb -> xa (prelu)
            f32x4 acc[4] = {};
            gemm16x64(xb, W1p, wave, lane, lq, quad, acc);
            store_act(xa, acc, col0, lq, quad, nullptr, pa1[0]);
        }
        __syncthreads();
        {   // layer 2 + Wo projection -> ang
            f32x4 acc[4] = {};
            gemm16x64(xa, W2p, wave, lane, lq, quad, acc);
            const float sl = pa2[0];
            float wo[4];
            #pragma unroll
            for (int f = 0; f < 4; ++f) wo[f] = Wo[col0 + f * 16 + lq];
            #pragma unroll
            for (int r = 0; r < 4; ++r) {
                float p = 0.f;
                #pragma unroll
                for (int f = 0; f < 4; ++f) {
                    float v = acc[f][r];
                    v = (v >= 0.f) ? v : sl * v;
                    p += v * wo[f];
                }
                #pragma unroll
                for (int m = 1; m < 16; m <<= 1) p += __shfl_xor(p, m, 64);
                if (lq == 0) s_ang[wave][quad * 4 + r] = p;
            }
        }
        __syncthreads();
        if (t < 16) {
            float s = bo[0];
            #pragma unroll
            for (int w2 = 0; w2 < 8; ++w2) s += s_ang[w2][t];
            ang[rb + t] = s;
        }
    } else {
        // build boolean adjacency bits — 128 blocks x 512 thr (Ab zeroed by prep)
        int base = (bx - MLP_BLOCKS) * 512 + t;
        for (int e = base; e < E_EDGES; e += 128 * 512) {
            int r = esrc[e], c = edst[e];
            atomicOr(&AbOut[(size_t)r * NWORDS + (c >> 5)], 1u << (c & 31));
        }
    }
}

// ---------------- row-OR body (shared by K3/K4 tails) ----------------
__device__ __forceinline__ void row_or(int row, int wave, int lane,
                                       int* s_cnt, int (*s_list)[256],
                                       const u32* __restrict__ P, const u32* __restrict__ Q,
                                       u32* __restrict__ BOut)
{
    if (lane == 0) s_cnt[wave] = 0;
    __syncthreads();
    const u32* prow = P + (size_t)row * NWORDS;
    #pragma unroll
    for (int h = 0; h < 2; ++h) {
        u32 bits = prow[h * 64 + lane];
        int base = (h * 64 + lane) * 32;
        while (bits) {
            int b = __ffs(bits) - 1; bits &= bits - 1;
            int pos = atomicAdd(&s_cnt[wave], 1);
            if (pos < 256) s_list[wave][pos] = base + b;
        }
    }
    __syncthreads();
    int cnt = min(s_cnt[wave], 256);
    u32 acc0 = 0, acc1 = 0;
    int j = 0;
    for (; j + 4 <= cnt; j += 4) {
        int i0 = s_list[wave][j], i1 = s_list[wave][j + 1];
        int i2 = s_list[wave][j + 2], i3 = s_list[wave][j + 3];
        const u32* q0 = Q + (size_t)i0 * NWORDS;
        const u32* q1 = Q + (size_t)i1 * NWORDS;
        const u32* q2 = Q + (size_t)i2 * NWORDS;
        const u32* q3 = Q + (size_t)i3 * NWORDS;
        u32 x0 = q0[lane], x1 = q1[lane], x2 = q2[lane], x3 = q3[lane];
        u32 y0 = q0[64 + lane], y1 = q1[64 + lane], y2 = q2[64 + lane], y3 = q3[64 + lane];
        acc0 |= x0 | x1 | x2 | x3;
        acc1 |= y0 | y1 | y2 | y3;
    }
    for (; j < cnt; ++j) {
        const u32* q = Q + (size_t)s_list[wave][j] * NWORDS;
        acc0 |= q[lane]; acc1 |= q[64 + lane];
    }
    BOut[(size_t)row * NWORDS + lane]      = acc0;
    BOut[(size_t)row * NWORDS + 64 + lane] = acc1;
}

// ---------------- K3: hop1 edge scatter (512 blocks) + A2 = bool(A@A) (1024 blocks) ----------------
__global__ __launch_bounds__(256)
void hop1_rowor(const int* __restrict__ src, const int* __restrict__ dst,
                const float* __restrict__ ang, float* __restrict__ h1,
                const u32* __restrict__ P, const u32* __restrict__ Q, u32* __restrict__ BOut)
{
    __shared__ int s_cnt[4];
    __shared__ int s_list[4][256];
    const int bx = blockIdx.x, t = threadIdx.x;
    const int wave = t >> 6, lane = t & 63;
    if (bx < 512) {
        int e = bx * 256 + t;
        atomicAdd(&h1[src[e]], 0.25f * ang[dst[e]]);
    } else {
        row_or((bx - 512) * 4 + wave, wave, lane, s_cnt, s_list, P, Q, BOut);
    }
}

// ---------------- K4: bmv2 (1024 blocks) + A3 = bool(A@A2) (1024 blocks) ----------------
// bmv2: a2[i] = a1(i) + (1/9)*sum_{j in A2-row(i)} a1(j); a1 = ang + h1, staged in LDS (r4).
__global__ __launch_bounds__(256)
void bmv2_rowor(const u32* __restrict__ A2, const float* __restrict__ ang,
                const float* __restrict__ h1, float* __restrict__ a2,
                float* __restrict__ Tpart,
                const u32* __restrict__ P, const u32* __restrict__ Q, u32* __restrict__ BOut)
{
    __shared__ float aLds[N_NODES];   // 16 KiB
    __shared__ float s_red[4];
    __shared__ int s_cnt[4];
    __shared__ int s_list[4][256];
    const int bx = blockIdx.x, t = threadIdx.x;
    const int wave = t >> 6, lane = t & 63;

    if (bx < 1024) {
        #pragma unroll
        for (int i = 0; i < 4; ++i) {
            int e = (i * 256 + t) * 4;
            float4 va = *(const float4*)(ang + e);
            float4 vh = *(const float4*)(h1 + e);
            float4 o; o.x = va.x + vh.x; o.y = va.y + vh.y; o.z = va.z + vh.z; o.w = va.w + vh.w;
            *(float4*)(aLds + e) = o;
        }
        __syncthreads();

        int row = bx * 4 + wave;
        float s = 0.f;
        #pragma unroll
        for (int h = 0; h < 2; ++h) {
            u32 bits = A2[(size_t)row * NWORDS + h * 64 + lane];
            int base = (h * 64 + lane) * 32;
            while (bits) {
                int b = __ffs(bits) - 1;
                bits &= bits - 1;
                s += aLds[base + b];
            }
        }
        #pragma unroll
        for (int off = 32; off > 0; off >>= 1) s += __shfl_down(s, off, 64);
        if (lane == 0) {
            float val = aLds[row] + (1.f / 9.f) * s;
            a2[row] = val;
            s_red[wave] = val;
        }
        __syncthreads();
        if (t == 0)
            Tpart[bx] = s_red[0] + s_red[1] + s_red[2] + s_red[3];
    } else {
        row_or((bx - 1024) * 4 + wave, wave, lane, s_cnt, s_list, P, Q, BOut);
    }
}

// ---------------- K5: out[i] = a2[i] + (1/16)*(T - sum_{j NOT in A3-row(i)} a2[j]) ----------------
__global__ __launch_bounds__(256)
void bits_matvec3(const u32* __restrict__ A3, const float* __restrict__ a2,
                  const float* __restrict__ Tpart, float* __restrict__ out)
{
    __shared__ float aLds[N_NODES];   // 16 KiB
    __shared__ float s_part[4];
    const int t = threadIdx.x, wave = t >> 6, lane = t & 63;

    #pragma unroll
    for (int i = 0; i < 4; ++i) {
        int e = (i * 256 + t) * 4;
        *(float4*)(aLds + e) = *(const float4*)(a2 + e);
    }

    float tsum = 0.f;
    #pragma unroll
    for (int i = 0; i < 4; ++i) tsum += Tpart[i * 256 + t];
    #pragma unroll
    for (int off = 32; off > 0; off >>= 1) tsum += __shfl_down(tsum, off, 64);
    if (lane == 0) s_part[wave] = tsum;
    __syncthreads();                      // covers aLds stage + s_part
    const float T = s_part[0] + s_part[1] + s_part[2] + s_part[3];

    int row = blockIdx.x * 4 + wave;
    float s = 0.f;
    #pragma unroll
    for (int h = 0; h < 2; ++h) {
        u32 bits = ~A3[(size_t)row * NWORDS + h * 64 + lane];   // complement (~97% dense)
        int base = (h * 64 + lane) * 32;
        while (bits) {
            int b = __ffs(bits) - 1;
            bits &= bits - 1;
            s += aLds[base + b];
        }
    }
    #pragma unroll
    for (int off = 32; off > 0; off >>= 1) s += __shfl_down(s, off, 64);
    if (lane == 0) out[row] = aLds[row] + (1.f / 16.f) * (T - s);
}

extern "C" void kernel_launch(void* const* d_in, const int* in_sizes, int n_in,
                              void* d_out, int out_size, void* d_ws, size_t ws_size,
                              hipStream_t stream) {
    const float* coeffs = (const float*)d_in[0];
    const int*   edges  = (const int*)d_in[1];
    const float* W0     = (const float*)d_in[2];
    const float* b0     = (const float*)d_in[3];
    const float* pa0    = (const float*)d_in[4];
    const float* W1     = (const float*)d_in[5];
    const float* pa1    = (const float*)d_in[6];
    const float* W2     = (const float*)d_in[7];
    const float* pa2    = (const float*)d_in[8];
    const float* Wo     = (const float*)d_in[9];
    const float* bo     = (const float*)d_in[10];
    float* out = (float*)d_out;

    char* ws = (char*)d_ws;
    bf16*  W0p  = (bf16*)(ws + OFF_W0P);
    bf16*  W1p  = (bf16*)(ws + OFF_W1P);
    bf16*  W2p  = (bf16*)(ws + OFF_W2P);
    float* ang  = (float*)(ws + OFF_ANG);
    float* h1   = (float*)(ws + OFF_H1);
    float* a2v  = (float*)(ws + OFF_A2V);
    float* Tp   = (float*)(ws + OFF_TP);
    u32*   Ab   = (u32*)(ws + OFF_AB);
    u32*   A2b  = (u32*)(ws + OFF_A2B);
    u32*   A3b  = (u32*)(ws + OFF_A3B);

    const int* srcp = edges;
    const int* dstp = edges + E_EDGES;

    // K1: pack W0/W1/W2 into fragment-ready bf16 layout, zero Ab, zero h1
    prep<<<321, 256, 0, stream>>>(W0, W1, W2, W0p, W1p, W2p, Ab, h1);

    // K2: row-local fused MLP (coeffs -> ang, plain stores) + adj-build
    mlp_fused<<<MLP_BLOCKS + 128, 512, 0, stream>>>(coeffs, W0p, W1p, W2p, b0, pa0, pa1, pa2,
                                                    Wo, bo, ang, srcp, dstp, Ab);

    // K3: hop1 scatter (needs ang) + A2 = bool(A@A) (needs Ab)
    hop1_rowor<<<1536, 256, 0, stream>>>(srcp, dstp, ang, h1, Ab, Ab, A2b);

    // K4: bmv2 (needs h1, A2) + A3 = bool(A@A2)
    bmv2_rowor<<<2048, 256, 0, stream>>>(A2b, ang, h1, a2v, Tp, Ab, A2b, A3b);

    // K5: bmv3
    bits_matvec3<<<1024, 256, 0, stream>>>(A3b, a2v, Tp, out);
}